// Round 1
// baseline (114.609 us; speedup 1.0000x reference)
//
#include <hip/hip_runtime.h>

#define IMG_H 1080
#define IMG_W 1920
#define TILE_W 128
#define TILE_H 32
#define SW 134           // TILE_W + 6 (halo 3 each side)
#define SH 38            // TILE_H + 6
#define SP 136           // padded LDS row stride (floats), keeps 16B alignment

// 9-consecutive-set-bits (circular over 16) detector.
// Matches reference: buffer24 = m | (m & 0xFF) << 16, windows i=0..15 of 9 bits.
__device__ __forceinline__ unsigned det9(unsigned m) {
    unsigned x = m | (m << 16);      // bits 16..23 replicate m[0..7]; 24..31 harmless
    unsigned t = x & (x >> 1);       // runs of 2
    t &= t >> 2;                     // runs of 4
    t &= t >> 4;                     // runs of 8
    t &= x >> 8;                     // runs of 9
    return t & 0xFFFFu;              // window starts 0..15
}

__global__ __launch_bounds__(256) void fast_score_kernel(const float* __restrict__ img,
                                                         float* __restrict__ out) {
    __shared__ float sm[SH * SP];

    const int n  = blockIdx.z;
    const int x0 = blockIdx.x * TILE_W;   // tile origin (image coords)
    const int y0 = blockIdx.y * TILE_H;
    const int tid = threadIdx.x;

    const float* in = img + (size_t)n * (IMG_H * IMG_W);
    float* op = out + (size_t)n * (IMG_H * IMG_W);

    // ---- stage tile + halo into LDS (replicate-clamped) ----
    {
        const int lane = tid & 63;
        const int rgrp = tid >> 6;            // 4 row groups of 64 lanes
        for (int r = rgrp; r < SH; r += 4) {
            int gy = y0 - 3 + r;
            gy = min(max(gy, 0), IMG_H - 1);
            const float* rowp = in + (size_t)gy * IMG_W;
            for (int c = lane; c < SW; c += 64) {
                int gx = x0 - 3 + c;
                gx = min(max(gx, 0), IMG_W - 1);
                sm[r * SP + c] = rowp[gx];
            }
        }
    }
    __syncthreads();

    // ---- each thread computes a 4x4 output patch ----
    const int cg = tid & 31;     // 32 col groups * 4 = 128 cols
    const int rg = tid >> 5;     // 8 row groups * 4 = 32 rows
    const int C = cg * 4;        // tile-local col of first output
    const int R = rg * 4;        // tile-local row of first output

    // 10 rows x 12 cols register window covers all circle taps for the 4x4 patch
    float wv[10][12];
#pragma unroll
    for (int r = 0; r < 10; ++r) {
        const float* sp = &sm[(R + r) * SP + C];
        float4 a = *(const float4*)(sp);
        float4 b = *(const float4*)(sp + 4);
        float4 c4 = *(const float4*)(sp + 8);
        wv[r][0] = a.x;  wv[r][1] = a.y;  wv[r][2]  = a.z;  wv[r][3]  = a.w;
        wv[r][4] = b.x;  wv[r][5] = b.y;  wv[r][6]  = b.z;  wv[r][7]  = b.w;
        wv[r][8] = c4.x; wv[r][9] = c4.y; wv[r][10] = c4.z; wv[r][11] = c4.w;
    }

    constexpr int DY[16] = {0, 1, 2, 3, 3, 3, 2, 1, 0, -1, -2, -3, -3, -3, -2, -1};
    constexpr int DX[16] = {-3, -3, -2, -1, 0, 1, 2, 3, 3, 3, 2, 1, 0, -1, -2, -3};

#pragma unroll
    for (int rr = 0; rr < 4; ++rr) {
        const int gy = y0 + R + rr;
        float4 res;
        float* resp = &res.x;
#pragma unroll
        for (int cc = 0; cc < 4; ++cc) {
            const float center = wv[rr + 3][cc + 3];
            unsigned dark = 0u, bright = 0u;
#pragma unroll
            for (int k = 0; k < 16; ++k) {
                const float d = wv[rr + 3 + DY[k]][cc + 3 + DX[k]] - center;
                dark   |= (d >=  20.0f ? 1u : 0u) << k;
                bright |= (d <= -20.0f ? 1u : 0u) << k;
            }
            resp[cc] = (det9(dark) | det9(bright)) ? 1.0f : 0.0f;
        }
        if (gy < IMG_H) {
            *(float4*)(op + (size_t)gy * IMG_W + (x0 + C)) = res;
        }
    }
}

extern "C" void kernel_launch(void* const* d_in, const int* in_sizes, int n_in,
                              void* d_out, int out_size, void* d_ws, size_t ws_size,
                              hipStream_t stream) {
    const float* img = (const float*)d_in[0];
    float* out = (float*)d_out;
    const int n_img = in_sizes[0] / (IMG_H * IMG_W);   // = 4
    dim3 grid((IMG_W + TILE_W - 1) / TILE_W,           // 15
              (IMG_H + TILE_H - 1) / TILE_H,           // 34
              n_img);
    fast_score_kernel<<<grid, 256, 0, stream>>>(img, out);
}